// Round 6
// baseline (903.778 us; speedup 1.0000x reference)
//
#include <hip/hip_runtime.h>
#include <hip/hip_bf16.h>
#include <math.h>

using bf16 = __hip_bfloat16;

#define DEV static __device__ __forceinline__

constexpr int NENT = 40000;
constexpr int DIM  = 200;
constexpr int EE   = 80000;      // edges per side
constexpr int TOTE = 2 * EE;     // 160000
constexpr int BQ   = 1024;
constexpr float EPSBN = 1e-5f;
constexpr size_t XOFF = (size_t)2 * BQ * DIM;   // x-region element offset inside d_out

// MFMA geometry: N padded to 208 (13x16), K padded to 224 (7x32)
constexpr int KP   = 224;
constexpr int NP   = 208;
constexpr int LDAS = 232;        // LDS A stride (ushorts): 464B rows -> 2-way-max bank aliasing
constexpr int MT_LOOP = (NENT + 127) / 128;  // 313 (loop kernel M=128)
constexpr int MT_SIDE = EE / 64;             // 1250 per side; merged edge grid = 2500

typedef __attribute__((ext_vector_type(8))) short s8v;   // 8 x bf16 (4 VGPRs)
typedef __attribute__((ext_vector_type(4))) float f4v;   // MFMA accumulator
typedef __attribute__((ext_vector_type(4))) unsigned short us4;  // 4 x bf16 (8B)

struct MP { const void* p; };    // world-dtype (bf16|f32) pointer, runtime flag

DEV float b2f(unsigned int u) { union { unsigned int i; float f; } v; v.i = u << 16; return v.f; }

DEV float ld(MP m, size_t i, int bf) {
  return bf ? b2f(((const unsigned short*)m.p)[i]) : ((const float*)m.p)[i];
}
DEV void ld8(MP m, size_t i, float* o, int bf) {
  if (bf) {
    uint4 u = *(const uint4*)((const unsigned short*)m.p + i);
    o[0]=b2f(u.x & 0xffffu); o[1]=b2f(u.x >> 16);
    o[2]=b2f(u.y & 0xffffu); o[3]=b2f(u.y >> 16);
    o[4]=b2f(u.z & 0xffffu); o[5]=b2f(u.z >> 16);
    o[6]=b2f(u.w & 0xffffu); o[7]=b2f(u.w >> 16);
  } else {
    const float4* q = (const float4*)((const float*)m.p + i);
    float4 a = q[0], b = q[1];
    o[0]=a.x; o[1]=a.y; o[2]=a.z; o[3]=a.w; o[4]=b.x; o[5]=b.y; o[6]=b.z; o[7]=b.w;
  }
}
DEV void f32load8(const float* p, float* o) {
  const float4* q = (const float4*)p;
  float4 a = q[0], b = q[1];
  o[0]=a.x; o[1]=a.y; o[2]=a.z; o[3]=a.w; o[4]=b.x; o[5]=b.y; o[6]=b.z; o[7]=b.w;
}
DEV void st(void* p, size_t i, float v, int bf) {
  if (bf) ((bf16*)p)[i] = __float2bfloat16(v);
  else    ((float*)p)[i] = v;
}
DEV unsigned short f2b(float f) {   // RNE f32 -> bf16 bits (inputs never NaN)
  union { float f; unsigned int i; } v; v.f = f;
  return (unsigned short)((v.i + 0x7fffu + ((v.i >> 16) & 1u)) >> 16);
}
DEV uint4 pack8(const float* o) {
  uint4 u;
  u.x = (unsigned)f2b(o[0]) | ((unsigned)f2b(o[1]) << 16);
  u.y = (unsigned)f2b(o[2]) | ((unsigned)f2b(o[3]) << 16);
  u.z = (unsigned)f2b(o[4]) | ((unsigned)f2b(o[5]) << 16);
  u.w = (unsigned)f2b(o[6]) | ((unsigned)f2b(o[7]) << 16);
  return u;
}

// ---------------- dtype detect ----------------
__global__ void detect_kernel(const unsigned short* __restrict__ e, int* __restrict__ flag) {
  int tid = threadIdx.x;
  int absurd = 0;
  for (int i = tid; i < 2048; i += 64) {
    int ex = (e[i] >> 7) & 0xFF;
    if (ex >= 0xD0 || (ex != 0 && ex <= 0x50)) absurd++;
  }
  for (int o = 32; o; o >>= 1) absurd += __shfl_down(absurd, o);
  if (tid == 0) *flag = (absurd > 64) ? 0 : 1;   // 1 => bf16 world
}

// ---------------- small kernels ----------------
// fused: src-degree histograms (per side) + dst counting-sort histogram (per side)
__global__ void edge_hist_kernel(const int* __restrict__ ei,
                                 float* __restrict__ deg_in, float* __restrict__ deg_out,
                                 int* __restrict__ cnt) {
  int i = blockIdx.x * 256 + threadIdx.x;
  if (i >= TOTE) return;
  atomicAdd((i < EE ? deg_in : deg_out) + ei[i], 1.0f);
  int side = (i >= EE) ? 1 : 0;
  atomicAdd(cnt + side * NENT + ei[TOTE + i], 1);
}

__global__ void norm_kernel(const int* __restrict__ ei,
                            const float* __restrict__ deg_in, const float* __restrict__ deg_out,
                            float* __restrict__ normA) {
  int i = blockIdx.x * 256 + threadIdx.x;
  if (i >= TOTE) return;
  int s = ei[i], d = ei[TOTE + i];
  const float* deg = (i < EE) ? deg_in : deg_out;
  float a = deg[s], b = deg[d];
  float na = a > 0.f ? rsqrtf(a) : 0.f;
  float nb = b > 0.f ? rsqrtf(b) : 0.f;
  normA[i] = na * nb;
}

// 2 blocks (one per side), 256 threads: exclusive scan of cnt -> offs (+copy to tmpo)
__global__ __launch_bounds__(256) void scan_kernel(const int* __restrict__ cnt,
                                                   int* __restrict__ offs,
                                                   int* __restrict__ tmpo) {
  __shared__ int part[256];
  const int side = blockIdx.x;
  const int* c = cnt + side * NENT;
  int* o  = offs + side * (NENT + 1);
  int* tp = tmpo + side * NENT;
  const int t = threadIdx.x;
  const int CH = (NENT + 255) / 256;           // 157
  int lo = t * CH; if (lo > NENT) lo = NENT;
  int hi = lo + CH; if (hi > NENT) hi = NENT;
  int s = 0;
  for (int i = lo; i < hi; ++i) s += c[i];
  part[t] = s;
  __syncthreads();
  for (int d = 1; d < 256; d <<= 1) {
    int v = (t >= d) ? part[t - d] : 0;
    __syncthreads();
    part[t] += v;
    __syncthreads();
  }
  int run = (t == 0) ? 0 : part[t - 1];
  for (int i = lo; i < hi; ++i) { o[i] = run; tp[i] = run; run += c[i]; }
  if (t == 255) o[NENT] = run;                 // == EE
}

__global__ void scatter_kernel(const int* __restrict__ ei, int* __restrict__ tmpo,
                               int* __restrict__ perm) {
  int i = blockIdx.x * 256 + threadIdx.x;
  if (i >= TOTE) return;
  int side = (i >= EE) ? 1 : 0;
  int d = ei[TOTE + i];
  int p = atomicAdd(tmpo + side * NENT + d, 1);
  perm[side * EE + p] = i;
}

__global__ void copy_f32_kernel(MP s, float* __restrict__ d, int n, const int* __restrict__ flagp) {
  int bf = *flagp;
  int i = blockIdx.x * 256 + threadIdx.x;
  if (i < n) d[i] = ld(s, i, bf);
}

__global__ void mat200_kernel(MP A, int a_use_flag, MP B, float* __restrict__ C,
                              const int* __restrict__ flagp) {
  int bf = *flagp;
  int abf = a_use_flag ? bf : 0;
  int i = blockIdx.x, c = threadIdx.x;
  if (c >= DIM) return;
  float acc = 0.f;
  for (int d = 0; d < DIM; ++d)
    acc = fmaf(ld(A, (size_t)i * DIM + d, abf), ld(B, (size_t)d * DIM + c, bf), acc);
  C[(size_t)i * DIM + c] = acc;
}

// Bt[n][k] = W^T padded to [208][224] bf16, optionally folding loop_rel; all 8 in one launch
struct BtArgs { const void* w[8]; const void* lr[8]; int has[8]; };
__global__ void btprep_all_kernel(BtArgs a, unsigned short* __restrict__ bt,
                                  const int* __restrict__ flagp) {
  int bf = *flagp;
  int m = blockIdx.y;            // matrix index 0..7
  int n = blockIdx.x, k = threadIdx.x;
  if (k >= KP) return;
  float v = 0.f;
  if (n < DIM && k < DIM) {
    MP w = { a.w[m] };
    v = ld(w, (size_t)k * DIM + n, bf);
    if (a.has[m]) { MP l = { a.lr[m] }; v *= ld(l, k, bf); }
  }
  bt[((size_t)m * NP + n) * KP + k] = f2b(v);
}

// ---------------- fused loop GEMM + segmented msg sum ----------------
// agg[e] = (x[e]*loop_rel)@w_loop  +  sum msgIn[offsI[e]:offsI[e+1]]  +  sum msgOut[...]
// TRANSPOSED MFMA (mfma(Bt_frag, A_frag)): acc[mt][nt][i] = D[entity = m0+wm*64+mt*16+col]
//                                                            [n = (wn*7+nt)*16 + quad*4 + i]
// -> each lane owns 4 contiguous cols of one entity; msg segments (dst-sorted, contiguous)
// accumulate straight into the MFMA accumulator with 8B us4 loads; one float4 store per tile.
// Addition order per element identical to the old loop_mfma->segsum pair (loop value first,
// then in-side msgs k-ascending, then out-side) -> bit-identical results.
__global__ __launch_bounds__(256, 2) void loop_seg(
    MP x, size_t xoff, const unsigned short* __restrict__ Bt,
    const unsigned short* __restrict__ msg,
    const int* __restrict__ offsI, const int* __restrict__ offsO,
    float* __restrict__ agg, const int* __restrict__ flagp) {
  __shared__ unsigned short As[128][LDAS];
  const int bf  = *flagp;
  const int tid = threadIdx.x;
  const int m0  = blockIdx.x * 128;

  for (int i = tid; i < 128 * 28; i += 256) {
    int r = i / 28, cg = i - r * 28;
    float o[8] = {0,0,0,0,0,0,0,0};
    int row = m0 + r;
    if (row < NENT && cg < 25) ld8(x, xoff + (size_t)row * DIM + cg * 8, o, bf);
    *(uint4*)&As[r][cg * 8] = pack8(o);
  }
  __syncthreads();

  const int lane = tid & 63;
  const int w    = tid >> 6;
  const int wm   = w & 1;          // M-half: rows [wm*64, wm*64+64)
  const int wn   = w >> 1;         // N-half: nt' = wn*7 + nt
  const int col  = lane & 15;
  const int quad = lane >> 4;
  const int rbase = wm * 64;
  const unsigned short* btl = Bt + (size_t)(wn * 7 * 16 + col) * KP + quad * 8;

  f4v acc[4][7];
#pragma unroll
  for (int mt = 0; mt < 4; ++mt)
#pragma unroll
    for (int nt = 0; nt < 7; ++nt) acc[mt][nt] = (f4v){0.f, 0.f, 0.f, 0.f};

#pragma unroll
  for (int kc = 0; kc < 7; ++kc) {
    const int k0 = kc * 32;
    s8v a0 = __builtin_bit_cast(s8v, *(const uint4*)&As[rbase +      col][k0 + quad * 8]);
    s8v a1 = __builtin_bit_cast(s8v, *(const uint4*)&As[rbase + 16 + col][k0 + quad * 8]);
    s8v a2 = __builtin_bit_cast(s8v, *(const uint4*)&As[rbase + 32 + col][k0 + quad * 8]);
    s8v a3 = __builtin_bit_cast(s8v, *(const uint4*)&As[rbase + 48 + col][k0 + quad * 8]);
#pragma unroll
    for (int nt = 0; nt < 7; ++nt) {
      if (wn == 0 || nt < 6) {     // nt' < 13
        s8v b = __builtin_bit_cast(s8v, *(const uint4*)(btl + (size_t)nt * 16 * KP + k0));
        acc[0][nt] = __builtin_amdgcn_mfma_f32_16x16x32_bf16(b, a0, acc[0][nt], 0, 0, 0);
        acc[1][nt] = __builtin_amdgcn_mfma_f32_16x16x32_bf16(b, a1, acc[1][nt], 0, 0, 0);
        acc[2][nt] = __builtin_amdgcn_mfma_f32_16x16x32_bf16(b, a2, acc[2][nt], 0, 0, 0);
        acc[3][nt] = __builtin_amdgcn_mfma_f32_16x16x32_bf16(b, a3, acc[3][nt], 0, 0, 0);
      }
    }
  }

  // fused segment sums + store (each lane: entity e, cols n0..n0+3 per nt)
#pragma unroll
  for (int mt = 0; mt < 4; ++mt) {
    const int e = m0 + rbase + mt * 16 + col;
    if (e < NENT) {
      const int bI = offsI[e], eI = offsI[e + 1];
      const int bO = offsO[e], eO = offsO[e + 1];
      for (int k = bI; k < eI; ++k) {
        const unsigned short* mr = msg + (size_t)k * DIM;
#pragma unroll
        for (int nt = 0; nt < 7; ++nt) {
          const int n0 = (wn * 7 + nt) * 16 + quad * 4;
          if (n0 < DIM) {
            us4 u = *(const us4*)(mr + n0);
            acc[mt][nt][0] += b2f(u[0]); acc[mt][nt][1] += b2f(u[1]);
            acc[mt][nt][2] += b2f(u[2]); acc[mt][nt][3] += b2f(u[3]);
          }
        }
      }
      for (int k = bO; k < eO; ++k) {
        const unsigned short* mr = msg + (size_t)(EE + k) * DIM;
#pragma unroll
        for (int nt = 0; nt < 7; ++nt) {
          const int n0 = (wn * 7 + nt) * 16 + quad * 4;
          if (n0 < DIM) {
            us4 u = *(const us4*)(mr + n0);
            acc[mt][nt][0] += b2f(u[0]); acc[mt][nt][1] += b2f(u[1]);
            acc[mt][nt][2] += b2f(u[2]); acc[mt][nt][3] += b2f(u[3]);
          }
        }
      }
#pragma unroll
      for (int nt = 0; nt < 7; ++nt) {
        const int n0 = (wn * 7 + nt) * 16 + quad * 4;
        if (n0 < DIM) {
          float4 t;
          t.x = acc[mt][nt][0]; t.y = acc[mt][nt][1];
          t.z = acc[mt][nt][2]; t.w = acc[mt][nt][3];
          *(float4*)&agg[(size_t)e * DIM + n0] = t;
        }
      }
    }
  }
}

// ---------------- phase A (merged sides, 8 waves, 2Mx4N): qual GEMM -> m (LDS) -> msg GEMM ----
// grid = 2*MT_SIDE x 512 threads: blocks [0,1250) in-side, [1250,2500) out-side.
// TRANSPOSED MFMA: acc[mt][nt][i] = D[edge = wm*32+mt*16+col][n = (ntBase+nt)*16 + quad*4 + i]
// 8-wave split: wm in {0,1} (32 rows), wn in {0..3} with nt counts 4/3/3/3 -> acc[2][4] = 32
// AGPR (vs 56), ~82 regs/wave -> 6 waves/SIMD -> 24 waves/CU (75% occupancy, was 50%).
// Per-block B traffic unchanged (each Bt quarter read by the 2 wm-waves).
// K-order per output element unchanged -> bit-identical results vs round 5.
__global__ __launch_bounds__(512, 6) void edge_msg(
    MP x, size_t xoff, const float* __restrict__ re,
    const int* __restrict__ ei, const int* __restrict__ ety,
    const int* __restrict__ qe, const int* __restrict__ qr,
    const float* __restrict__ normA, const int* __restrict__ perm,
    const unsigned short* __restrict__ BtQ,
    const unsigned short* __restrict__ BtIn, const unsigned short* __restrict__ BtOut,
    unsigned short* __restrict__ msg, const int* __restrict__ flagp) {
  __shared__ unsigned short As[64][LDAS];           // 29.7 KB
  __shared__ int sQe0[64], sQe1[64], sQr0[64], sQr1[64], sSrc[64], sEty[64];
  __shared__ float sN[64];

  const int bf  = *flagp;
  const int tid = threadIdx.x;
  const int bid  = blockIdx.x;
  const int side = (bid >= MT_SIDE) ? 1 : 0;
  const int m0   = (bid - side * MT_SIDE) * 64;     // position within this side's sorted order
  const int* permS = perm + side * EE;
  const unsigned short* BtW = side ? BtOut : BtIn;
  const size_t mrow0 = (size_t)side * EE + m0;      // msg row base (side-major layout)

  if (tid < 64) {
    int e = permS[m0 + tid];                        // original edge id
    sQe0[tid] = qe[e];        sQe1[tid] = qe[TOTE + e];
    sQr0[tid] = qr[e];        sQr1[tid] = qr[TOTE + e];
    sSrc[tid] = ei[e];        sEty[tid] = ety[e];
    sN[tid]   = normA[e];
  }
  __syncthreads();

  // stage t1 = sum_q x[qe]*re[qr] into As (64 x 224 bf16), pad cols zeroed
  for (int i = tid; i < 64 * 28; i += 512) {
    int r = i / 28, cg = i - r * 28;
    float o[8] = {0,0,0,0,0,0,0,0};
    if (cg < 25) {
      float xa[8], ra[8], xb[8], rb[8];
      ld8(x, xoff + (size_t)sQe0[r] * DIM + cg * 8, xa, bf);
      f32load8(re + (size_t)sQr0[r] * DIM + cg * 8, ra);
      ld8(x, xoff + (size_t)sQe1[r] * DIM + cg * 8, xb, bf);
      f32load8(re + (size_t)sQr1[r] * DIM + cg * 8, rb);
#pragma unroll
      for (int j = 0; j < 8; ++j) o[j] = xa[j] * ra[j] + xb[j] * rb[j];
    }
    *(uint4*)&As[r][cg * 8] = pack8(o);
  }
  __syncthreads();

  const int lane = tid & 63;
  const int w    = tid >> 6;        // 0..7
  const int wm   = w & 1;           // M-half: rows [wm*32, wm*32+32)
  const int wn   = w >> 1;          // N-quarter
  const int ntBase = (wn == 0) ? 0 : 3 * wn + 1;   // 0,4,7,10
  const int ntCnt  = (wn == 0) ? 4 : 3;
  const int col  = lane & 15;
  const int quad = lane >> 4;
  const int rbase = wm * 32;
  const int nb4  = quad * 4;

  f4v acc[2][4];
#pragma unroll
  for (int mt = 0; mt < 2; ++mt)
#pragma unroll
    for (int nt = 0; nt < 4; ++nt) acc[mt][nt] = (f4v){0.f, 0.f, 0.f, 0.f};

  // GEMM 1 (transposed): acc[mt][nt] = qual^T tile
  {
    const unsigned short* btl = BtQ + (size_t)(ntBase * 16 + col) * KP + quad * 8;
#pragma unroll
    for (int kc = 0; kc < 7; ++kc) {
      const int k0 = kc * 32;
      s8v a0 = __builtin_bit_cast(s8v, *(const uint4*)&As[rbase +      col][k0 + quad * 8]);
      s8v a1 = __builtin_bit_cast(s8v, *(const uint4*)&As[rbase + 16 + col][k0 + quad * 8]);
#pragma unroll
      for (int nt = 0; nt < 4; ++nt) {
        if (nt < ntCnt) {
          s8v b = __builtin_bit_cast(s8v, *(const uint4*)(btl + (size_t)nt * 16 * KP + k0));
          acc[0][nt] = __builtin_amdgcn_mfma_f32_16x16x32_bf16(b, a0, acc[0][nt], 0, 0, 0);
          acc[1][nt] = __builtin_amdgcn_mfma_f32_16x16x32_bf16(b, a1, acc[1][nt], 0, 0, 0);
        }
      }
    }
  }
  __syncthreads();   // all GEMM1 reads of t1 complete before any ep1 overwrite

  // epilogue 1: m = x[src] * 0.5*(re[ety] + qual) -> As (8B vector ops)
#pragma unroll
  for (int mt = 0; mt < 2; ++mt) {
    const int erow = rbase + mt * 16 + col;
    const float* rerow = re + (size_t)sEty[erow] * DIM;
    const size_t xrow = xoff + (size_t)sSrc[erow] * DIM;
#pragma unroll
    for (int nt = 0; nt < 4; ++nt) {
      if (nt < ntCnt) {
        const int n0 = (ntBase + nt) * 16 + nb4;
        if (n0 < DIM) {                             // pads (>=200) stay zero from staging
          float xs[4];
          if (bf) {
            us4 u = *(const us4*)((const unsigned short*)x.p + xrow + n0);
            xs[0]=b2f(u[0]); xs[1]=b2f(u[1]); xs[2]=b2f(u[2]); xs[3]=b2f(u[3]);
          } else {
            float4 q = *(const float4*)((const float*)x.p + xrow + n0);
            xs[0]=q.x; xs[1]=q.y; xs[2]=q.z; xs[3]=q.w;
          }
          float4 r4 = *(const float4*)(rerow + n0);
          us4 mu;
          mu[0] = f2b(xs[0] * (0.5f * (r4.x + acc[mt][nt][0])));
          mu[1] = f2b(xs[1] * (0.5f * (r4.y + acc[mt][nt][1])));
          mu[2] = f2b(xs[2] * (0.5f * (r4.z + acc[mt][nt][2])));
          mu[3] = f2b(xs[3] * (0.5f * (r4.w + acc[mt][nt][3])));
          *(us4*)&As[erow][n0] = mu;
        }
      }
    }
  }
  __syncthreads();   // ep1 writes visible to all waves before GEMM2

#pragma unroll
  for (int mt = 0; mt < 2; ++mt)
#pragma unroll
    for (int nt = 0; nt < 4; ++nt) acc[mt][nt] = (f4v){0.f, 0.f, 0.f, 0.f};

  // GEMM 2 (transposed): msg^T = (w_in|w_out) @ m^T
  {
    const unsigned short* btl = BtW + (size_t)(ntBase * 16 + col) * KP + quad * 8;
#pragma unroll
    for (int kc = 0; kc < 7; ++kc) {
      const int k0 = kc * 32;
      s8v a0 = __builtin_bit_cast(s8v, *(const uint4*)&As[rbase +      col][k0 + quad * 8]);
      s8v a1 = __builtin_bit_cast(s8v, *(const uint4*)&As[rbase + 16 + col][k0 + quad * 8]);
#pragma unroll
      for (int nt = 0; nt < 4; ++nt) {
        if (nt < ntCnt) {
          s8v b = __builtin_bit_cast(s8v, *(const uint4*)(btl + (size_t)nt * 16 * KP + k0));
          acc[0][nt] = __builtin_amdgcn_mfma_f32_16x16x32_bf16(b, a0, acc[0][nt], 0, 0, 0);
          acc[1][nt] = __builtin_amdgcn_mfma_f32_16x16x32_bf16(b, a1, acc[1][nt], 0, 0, 0);
        }
      }
    }
  }

  // epilogue 2: msg[sorted_pos] = bf16(acc * norm), 8B vector stores
#pragma unroll
  for (int mt = 0; mt < 2; ++mt) {
    const int erow = rbase + mt * 16 + col;
    const float nv = sN[erow];
    unsigned short* mp = msg + (mrow0 + erow) * DIM;
#pragma unroll
    for (int nt = 0; nt < 4; ++nt) {
      if (nt < ntCnt) {
        const int n0 = (ntBase + nt) * 16 + nb4;
        if (n0 < DIM) {
          us4 mu;
          mu[0] = f2b(acc[mt][nt][0] * nv);
          mu[1] = f2b(acc[mt][nt][1] * nv);
          mu[2] = f2b(acc[mt][nt][2] * nv);
          mu[3] = f2b(acc[mt][nt][3] * nv);
          *(us4*)&mp[n0] = mu;
        }
      }
    }
  }
}

// ---------------- BatchNorm + gather ----------------
__global__ __launch_bounds__(256) void bn_reduce_kernel(const float* __restrict__ agg,
                                                        float* __restrict__ sums) {
  int tid = threadIdx.x;
  if (tid >= DIM) return;
  int row0 = blockIdx.x * 160;
  float s = 0.f, s2 = 0.f;
  for (int r = row0; r < row0 + 160; ++r) {
    float v = agg[(size_t)r * DIM + tid] * (1.f / 3.f);
    s += v; s2 += v * v;
  }
  atomicAdd(&sums[tid], s);
  atomicAdd(&sums[DIM + tid], s2);
}

__global__ __launch_bounds__(256) void bn_apply_kernel(const float* __restrict__ agg,
                                                       const float* __restrict__ sums,
                                                       MP gamma, MP beta,
                                                       void* __restrict__ xout, size_t ooff,
                                                       const int* __restrict__ flagp) {
  __shared__ float sc[DIM], sh[DIM];
  const int bf = *flagp;
  int tid = threadIdx.x;
  if (tid < DIM) {
    float mean = sums[tid] * (1.f / NENT);
    float var  = sums[DIM + tid] * (1.f / NENT) - mean * mean;
    float s = ld(gamma, tid, bf) * rsqrtf(var + EPSBN);
    sc[tid] = s;
    sh[tid] = ld(beta, tid, bf) - mean * s;
  }
  __syncthreads();
  int stride = gridDim.x * blockDim.x;
  for (int i = blockIdx.x * blockDim.x + tid; i < NENT * DIM; i += stride) {
    int c = i % DIM;
    float v = agg[i] * (1.f / 3.f);
    st(xout, ooff + i, tanhf(fmaf(v, sc[c], sh[c])), bf);
  }
}

__global__ void gather_kernel(void* __restrict__ out, const float* __restrict__ rfin,
                              const int* __restrict__ sub, const int* __restrict__ rel,
                              const int* __restrict__ flagp) {
  const int bf = *flagp;
  int i = blockIdx.x * 256 + threadIdx.x;
  MP xm; xm.p = out;
  if (i < BQ * DIM) {
    int b = i / DIM, c = i - b * DIM;
    st(out, i, ld(xm, XOFF + (size_t)sub[b] * DIM + c, bf), bf);
  } else if (i < 2 * BQ * DIM) {
    int j = i - BQ * DIM;
    int b = j / DIM, c = j - b * DIM;
    st(out, i, rfin[(size_t)rel[b] * DIM + c], bf);
  }
}

// ---------------- launch ----------------
extern "C" void kernel_launch(void* const* d_in, const int* in_sizes, int n_in,
                              void* d_out, int out_size, void* d_ws, size_t ws_size,
                              hipStream_t stream) {
  (void)in_sizes; (void)n_in; (void)out_size; (void)ws_size;
  const int* ei  = (const int*)d_in[0];
  const int* ety = (const int*)d_in[1];
  const int* qe  = (const int*)d_in[2];
  const int* qr  = (const int*)d_in[3];
  const int* sub = (const int*)d_in[4];
  const int* rel = (const int*)d_in[5];
  MP x0 = { d_in[6] };
  MP ir = { d_in[7] };
  MP w_rel[2]  = { { d_in[11] }, { d_in[20] } };
  MP gamma[2]  = { { d_in[15] }, { d_in[24] } };
  MP beta[2]   = { { d_in[16] }, { d_in[25] } };

  float* ws = (float*)d_ws;
  float* deg_in   = ws;                         // 40000
  float* deg_out  = ws + 40000;                 // 40000
  float* sums1    = ws + 80000;                 // 400
  float* sums2    = ws + 80400;                 // 400
  int*   flag     = (int*)(ws + 80800);         // 16
  float* normA    = ws + 80816;                 // 160000
  float* rel1     = ws + 240816;                // [200,200] f32
  float* rel2     = ws + 280816;
  float* rfin     = ws + 320816;
  unsigned short* bt = (unsigned short*)(ws + 440816);  // 8 x [208][224] bf16 -> ends 627184
  int*   cnt      = (int*)(ws + 627184);        // [2][40000]
  int*   offs     = (int*)(ws + 707184);        // [2][40001]
  int*   tmpo     = (int*)(ws + 787200);        // [2][40000]
  int*   perm     = (int*)(ws + 867200);        // [160000]
  unsigned short* msg = (unsigned short*)(ws + 1027200); // [160000][200] bf16, ends 17027200 < 18547184
  float* agg      = ws + 18547184;              // [40000][200] f32 (offset proven safe in r3)

  hipMemsetAsync(ws, 0, 80800 * sizeof(float), stream);       // deg + sums
  hipMemsetAsync(cnt, 0, 2 * NENT * sizeof(int), stream);     // dst counts

  detect_kernel<<<1, 64, 0, stream>>>((const unsigned short*)d_in[6], flag);
  edge_hist_kernel<<<(TOTE + 255) / 256, 256, 0, stream>>>(ei, deg_in, deg_out, cnt);
  norm_kernel<<<(TOTE + 255) / 256, 256, 0, stream>>>(ei, deg_in, deg_out, normA);
  scan_kernel<<<2, 256, 0, stream>>>(cnt, offs, tmpo);
  scatter_kernel<<<(TOTE + 255) / 256, 256, 0, stream>>>(ei, tmpo, perm);
  copy_f32_kernel<<<(DIM * DIM + 255) / 256, 256, 0, stream>>>(ir, rel1, DIM * DIM, flag);
  mat200_kernel<<<DIM, 256, 0, stream>>>(ir, 1, w_rel[0], rel2, flag);
  MP rel2m = { rel2 };
  mat200_kernel<<<DIM, 256, 0, stream>>>(rel2m, 0, w_rel[1], rfin, flag);

  // Bt: [0]=wq1 [1]=win1 [2]=wout1 [3]=wp1 [4]=wq2 [5]=win2 [6]=wout2 [7]=wp2 (one launch)
  BtArgs ba;
  ba.w[0] = d_in[12]; ba.lr[0] = nullptr;   ba.has[0] = 0;   // wq1
  ba.w[1] = d_in[9];  ba.lr[1] = nullptr;   ba.has[1] = 0;   // win1
  ba.w[2] = d_in[10]; ba.lr[2] = nullptr;   ba.has[2] = 0;   // wout1
  ba.w[3] = d_in[8];  ba.lr[3] = d_in[13];  ba.has[3] = 1;   // wp1 = w_loop1 * loop_rel1
  ba.w[4] = d_in[21]; ba.lr[4] = nullptr;   ba.has[4] = 0;   // wq2
  ba.w[5] = d_in[18]; ba.lr[5] = nullptr;   ba.has[5] = 0;   // win2
  ba.w[6] = d_in[19]; ba.lr[6] = nullptr;   ba.has[6] = 0;   // wout2
  ba.w[7] = d_in[17]; ba.lr[7] = d_in[22];  ba.has[7] = 1;   // wp2 = w_loop2 * loop_rel2
  btprep_all_kernel<<<dim3(NP, 8), 256, 0, stream>>>(ba, bt, flag);

  MP x1 = { d_out };
  const int* offsI = offs;
  const int* offsO = offs + (NENT + 1);

  // ---- layer 1 ----
  edge_msg<<<2 * MT_SIDE, 512, 0, stream>>>(x0, 0, rel1, ei, ety, qe, qr, normA, perm,
                                            bt + 0ull * NP * KP, bt + 1ull * NP * KP,
                                            bt + 2ull * NP * KP, msg, flag);
  loop_seg<<<MT_LOOP, 256, 0, stream>>>(x0, 0, bt + 3ull * NP * KP, msg, offsI, offsO, agg, flag);
  bn_reduce_kernel<<<NENT / 160, 256, 0, stream>>>(agg, sums1);
  bn_apply_kernel<<<2048, 256, 0, stream>>>(agg, sums1, gamma[0], beta[0], d_out, XOFF, flag);

  // ---- layer 2 (x1 lives in d_out x-region) ----
  edge_msg<<<2 * MT_SIDE, 512, 0, stream>>>(x1, XOFF, rel2, ei, ety, qe, qr, normA, perm,
                                            bt + 4ull * NP * KP, bt + 5ull * NP * KP,
                                            bt + 6ull * NP * KP, msg, flag);
  loop_seg<<<MT_LOOP, 256, 0, stream>>>(x1, XOFF, bt + 7ull * NP * KP, msg, offsI, offsO, agg, flag);
  bn_reduce_kernel<<<NENT / 160, 256, 0, stream>>>(agg, sums2);
  bn_apply_kernel<<<2048, 256, 0, stream>>>(agg, sums2, gamma[1], beta[1], d_out, XOFF, flag);

  gather_kernel<<<(2 * BQ * DIM + 255) / 256, 256, 0, stream>>>(d_out, rfin, sub, rel, flag);
}

// Round 7
// 782.353 us; speedup vs baseline: 1.1552x; 1.1552x over previous
//
#include <hip/hip_runtime.h>
#include <hip/hip_bf16.h>
#include <math.h>

using bf16 = __hip_bfloat16;

#define DEV static __device__ __forceinline__

constexpr int NENT = 40000;
constexpr int DIM  = 200;
constexpr int EE   = 80000;      // edges per side
constexpr int TOTE = 2 * EE;     // 160000
constexpr int BQ   = 1024;
constexpr float EPSBN = 1e-5f;
constexpr size_t XOFF = (size_t)2 * BQ * DIM;   // x-region element offset inside d_out

// MFMA geometry: N padded to 208 (13x16), K padded to 224 (7x32)
constexpr int KP   = 224;
constexpr int NP   = 208;
constexpr int LDAS = 232;        // LDS A stride (ushorts): 464B rows -> 2-way-max bank aliasing
constexpr int MT_LOOP = NENT / 64;           // 625 (loop kernel M=64)
constexpr int MT_SIDE = EE / 64;             // 1250 per side; merged edge grid = 2500

typedef __attribute__((ext_vector_type(8))) short s8v;   // 8 x bf16 (4 VGPRs)
typedef __attribute__((ext_vector_type(4))) float f4v;   // MFMA accumulator
typedef __attribute__((ext_vector_type(4))) unsigned short us4;  // 4 x bf16 (8B)

struct MP { const void* p; };    // world-dtype (bf16|f32) pointer, runtime flag

DEV float b2f(unsigned int u) { union { unsigned int i; float f; } v; v.i = u << 16; return v.f; }

DEV float ld(MP m, size_t i, int bf) {
  return bf ? b2f(((const unsigned short*)m.p)[i]) : ((const float*)m.p)[i];
}
DEV void ld8(MP m, size_t i, float* o, int bf) {
  if (bf) {
    uint4 u = *(const uint4*)((const unsigned short*)m.p + i);
    o[0]=b2f(u.x & 0xffffu); o[1]=b2f(u.x >> 16);
    o[2]=b2f(u.y & 0xffffu); o[3]=b2f(u.y >> 16);
    o[4]=b2f(u.z & 0xffffu); o[5]=b2f(u.z >> 16);
    o[6]=b2f(u.w & 0xffffu); o[7]=b2f(u.w >> 16);
  } else {
    const float4* q = (const float4*)((const float*)m.p + i);
    float4 a = q[0], b = q[1];
    o[0]=a.x; o[1]=a.y; o[2]=a.z; o[3]=a.w; o[4]=b.x; o[5]=b.y; o[6]=b.z; o[7]=b.w;
  }
}
DEV void f32load8(const float* p, float* o) {
  const float4* q = (const float4*)p;
  float4 a = q[0], b = q[1];
  o[0]=a.x; o[1]=a.y; o[2]=a.z; o[3]=a.w; o[4]=b.x; o[5]=b.y; o[6]=b.z; o[7]=b.w;
}
DEV void st(void* p, size_t i, float v, int bf) {
  if (bf) ((bf16*)p)[i] = __float2bfloat16(v);
  else    ((float*)p)[i] = v;
}
DEV unsigned short f2b(float f) {   // RNE f32 -> bf16 bits (inputs never NaN)
  union { float f; unsigned int i; } v; v.f = f;
  return (unsigned short)((v.i + 0x7fffu + ((v.i >> 16) & 1u)) >> 16);
}
DEV uint4 pack8(const float* o) {
  uint4 u;
  u.x = (unsigned)f2b(o[0]) | ((unsigned)f2b(o[1]) << 16);
  u.y = (unsigned)f2b(o[2]) | ((unsigned)f2b(o[3]) << 16);
  u.z = (unsigned)f2b(o[4]) | ((unsigned)f2b(o[5]) << 16);
  u.w = (unsigned)f2b(o[6]) | ((unsigned)f2b(o[7]) << 16);
  return u;
}

// ---------------- dtype detect ----------------
__global__ void detect_kernel(const unsigned short* __restrict__ e, int* __restrict__ flag) {
  int tid = threadIdx.x;
  int absurd = 0;
  for (int i = tid; i < 2048; i += 64) {
    int ex = (e[i] >> 7) & 0xFF;
    if (ex >= 0xD0 || (ex != 0 && ex <= 0x50)) absurd++;
  }
  for (int o = 32; o; o >>= 1) absurd += __shfl_down(absurd, o);
  if (tid == 0) *flag = (absurd > 64) ? 0 : 1;   // 1 => bf16 world
}

// ---------------- small kernels ----------------
// fused: src-degree histograms (per side) + dst counting-sort histogram (per side)
__global__ void edge_hist_kernel(const int* __restrict__ ei,
                                 float* __restrict__ deg_in, float* __restrict__ deg_out,
                                 int* __restrict__ cnt) {
  int i = blockIdx.x * 256 + threadIdx.x;
  if (i >= TOTE) return;
  atomicAdd((i < EE ? deg_in : deg_out) + ei[i], 1.0f);
  int side = (i >= EE) ? 1 : 0;
  atomicAdd(cnt + side * NENT + ei[TOTE + i], 1);
}

__global__ void norm_kernel(const int* __restrict__ ei,
                            const float* __restrict__ deg_in, const float* __restrict__ deg_out,
                            float* __restrict__ normA) {
  int i = blockIdx.x * 256 + threadIdx.x;
  if (i >= TOTE) return;
  int s = ei[i], d = ei[TOTE + i];
  const float* deg = (i < EE) ? deg_in : deg_out;
  float a = deg[s], b = deg[d];
  float na = a > 0.f ? rsqrtf(a) : 0.f;
  float nb = b > 0.f ? rsqrtf(b) : 0.f;
  normA[i] = na * nb;
}

// 2 blocks (one per side), 256 threads: exclusive scan of cnt -> offs (+copy to tmpo)
__global__ __launch_bounds__(256) void scan_kernel(const int* __restrict__ cnt,
                                                   int* __restrict__ offs,
                                                   int* __restrict__ tmpo) {
  __shared__ int part[256];
  const int side = blockIdx.x;
  const int* c = cnt + side * NENT;
  int* o  = offs + side * (NENT + 1);
  int* tp = tmpo + side * NENT;
  const int t = threadIdx.x;
  const int CH = (NENT + 255) / 256;           // 157
  int lo = t * CH; if (lo > NENT) lo = NENT;
  int hi = lo + CH; if (hi > NENT) hi = NENT;
  int s = 0;
  for (int i = lo; i < hi; ++i) s += c[i];
  part[t] = s;
  __syncthreads();
  for (int d = 1; d < 256; d <<= 1) {
    int v = (t >= d) ? part[t - d] : 0;
    __syncthreads();
    part[t] += v;
    __syncthreads();
  }
  int run = (t == 0) ? 0 : part[t - 1];
  for (int i = lo; i < hi; ++i) { o[i] = run; tp[i] = run; run += c[i]; }
  if (t == 255) o[NENT] = run;                 // == EE
}

__global__ void scatter_kernel(const int* __restrict__ ei, int* __restrict__ tmpo,
                               int* __restrict__ perm) {
  int i = blockIdx.x * 256 + threadIdx.x;
  if (i >= TOTE) return;
  int side = (i >= EE) ? 1 : 0;
  int d = ei[TOTE + i];
  int p = atomicAdd(tmpo + side * NENT + d, 1);
  perm[side * EE + p] = i;
}

__global__ void copy_f32_kernel(MP s, float* __restrict__ d, int n, const int* __restrict__ flagp) {
  int bf = *flagp;
  int i = blockIdx.x * 256 + threadIdx.x;
  if (i < n) d[i] = ld(s, i, bf);
}

__global__ void mat200_kernel(MP A, int a_use_flag, MP B, float* __restrict__ C,
                              const int* __restrict__ flagp) {
  int bf = *flagp;
  int abf = a_use_flag ? bf : 0;
  int i = blockIdx.x, c = threadIdx.x;
  if (c >= DIM) return;
  float acc = 0.f;
  for (int d = 0; d < DIM; ++d)
    acc = fmaf(ld(A, (size_t)i * DIM + d, abf), ld(B, (size_t)d * DIM + c, bf), acc);
  C[(size_t)i * DIM + c] = acc;
}

// Bt[n][k] = W^T padded to [208][224] bf16, optionally folding loop_rel; all 8 in one launch
struct BtArgs { const void* w[8]; const void* lr[8]; int has[8]; };
__global__ void btprep_all_kernel(BtArgs a, unsigned short* __restrict__ bt,
                                  const int* __restrict__ flagp) {
  int bf = *flagp;
  int m = blockIdx.y;            // matrix index 0..7
  int n = blockIdx.x, k = threadIdx.x;
  if (k >= KP) return;
  float v = 0.f;
  if (n < DIM && k < DIM) {
    MP w = { a.w[m] };
    v = ld(w, (size_t)k * DIM + n, bf);
    if (a.has[m]) { MP l = { a.lr[m] }; v *= ld(l, k, bf); }
  }
  bt[((size_t)m * NP + n) * KP + k] = f2b(v);
}

// ---------------- loop (self-edge) MFMA GEMM: agg = x @ wp'  (M=64, 2Mx2N, transposed) -------
// TRANSPOSED MFMA (verified bit-exact in r6): acc[mt][nt][i] = D[entity = m0+wm*32+mt*16+col]
//   [n = (wn*7+nt)*16 + quad*4 + i] -> lane owns 4 contiguous cols -> float4 stores.
// M=64 -> 625 blocks (2.4/CU) removes the 313-block tail imbalance of the M=128 version.
__global__ __launch_bounds__(256, 4) void loop_mfma(
    MP x, size_t xoff, const unsigned short* __restrict__ Bt,
    float* __restrict__ agg, const int* __restrict__ flagp) {
  __shared__ unsigned short As[64][LDAS];
  const int bf  = *flagp;
  const int tid = threadIdx.x;
  const int m0  = blockIdx.x * 64;

#pragma unroll
  for (int it = 0; it < 7; ++it) {
    int i = tid + it * 256;
    int r = i / 28, cg = i - r * 28;
    float o[8] = {0,0,0,0,0,0,0,0};
    if (cg < 25) ld8(x, xoff + (size_t)(m0 + r) * DIM + cg * 8, o, bf);
    *(uint4*)&As[r][cg * 8] = pack8(o);
  }
  __syncthreads();

  const int lane = tid & 63;
  const int w    = tid >> 6;
  const int wm   = w & 1;          // M-half: rows [wm*32, wm*32+32)
  const int wn   = w >> 1;         // N-half: nt' = wn*7 + nt (wn=1 does 6)
  const int col  = lane & 15;
  const int quad = lane >> 4;
  const int rbase = wm * 32;
  const unsigned short* btl = Bt + (size_t)(wn * 7 * 16 + col) * KP + quad * 8;

  f4v acc[2][7];
#pragma unroll
  for (int mt = 0; mt < 2; ++mt)
#pragma unroll
    for (int nt = 0; nt < 7; ++nt) acc[mt][nt] = (f4v){0.f, 0.f, 0.f, 0.f};

#pragma unroll
  for (int kc = 0; kc < 7; ++kc) {
    const int k0 = kc * 32;
    s8v a0 = __builtin_bit_cast(s8v, *(const uint4*)&As[rbase +      col][k0 + quad * 8]);
    s8v a1 = __builtin_bit_cast(s8v, *(const uint4*)&As[rbase + 16 + col][k0 + quad * 8]);
#pragma unroll
    for (int nt = 0; nt < 7; ++nt) {
      if (wn == 0 || nt < 6) {     // nt' < 13
        s8v b = __builtin_bit_cast(s8v, *(const uint4*)(btl + (size_t)nt * 16 * KP + k0));
        acc[0][nt] = __builtin_amdgcn_mfma_f32_16x16x32_bf16(b, a0, acc[0][nt], 0, 0, 0);
        acc[1][nt] = __builtin_amdgcn_mfma_f32_16x16x32_bf16(b, a1, acc[1][nt], 0, 0, 0);
      }
    }
  }

#pragma unroll
  for (int mt = 0; mt < 2; ++mt) {
    const int e = m0 + rbase + mt * 16 + col;      // < NENT always (625*64 = 40000)
#pragma unroll
    for (int nt = 0; nt < 7; ++nt) {
      const int n0 = (wn * 7 + nt) * 16 + quad * 4;
      if (n0 < DIM) {
        float4 t;
        t.x = acc[mt][nt][0]; t.y = acc[mt][nt][1];
        t.z = acc[mt][nt][2]; t.w = acc[mt][nt][3];
        *(float4*)&agg[(size_t)e * DIM + n0] = t;
      }
    }
  }
}

// ---------------- phase A (merged sides, 2Mx2N): qual GEMM -> rel_e -> m (LDS) -> msg GEMM ----
// EXACT round-5 structure (best measured: 146us/dispatch).
__global__ __launch_bounds__(256, 5) void edge_msg(
    MP x, size_t xoff, const float* __restrict__ re,
    const int* __restrict__ ei, const int* __restrict__ ety,
    const int* __restrict__ qe, const int* __restrict__ qr,
    const float* __restrict__ normA, const int* __restrict__ perm,
    const unsigned short* __restrict__ BtQ,
    const unsigned short* __restrict__ BtIn, const unsigned short* __restrict__ BtOut,
    unsigned short* __restrict__ msg, const int* __restrict__ flagp) {
  __shared__ unsigned short As[64][LDAS];           // 29.7 KB
  __shared__ int sQe0[64], sQe1[64], sQr0[64], sQr1[64], sSrc[64], sEty[64];
  __shared__ float sN[64];

  const int bf  = *flagp;
  const int tid = threadIdx.x;
  const int bid  = blockIdx.x;
  const int side = (bid >= MT_SIDE) ? 1 : 0;
  const int m0   = (bid - side * MT_SIDE) * 64;     // position within this side's sorted order
  const int* permS = perm + side * EE;
  const unsigned short* BtW = side ? BtOut : BtIn;
  const size_t mrow0 = (size_t)side * EE + m0;      // msg row base (side-major layout)

  if (tid < 64) {
    int e = permS[m0 + tid];                        // original edge id
    sQe0[tid] = qe[e];        sQe1[tid] = qe[TOTE + e];
    sQr0[tid] = qr[e];        sQr1[tid] = qr[TOTE + e];
    sSrc[tid] = ei[e];        sEty[tid] = ety[e];
    sN[tid]   = normA[e];
  }
  __syncthreads();

  // stage t1 = sum_q x[qe]*re[qr] into As (64 x 224 bf16), pad cols zeroed
#pragma unroll
  for (int it = 0; it < 7; ++it) {
    int i = tid + it * 256;
    int r = i / 28, cg = i - r * 28;
    float o[8] = {0,0,0,0,0,0,0,0};
    if (cg < 25) {
      float xa[8], ra[8], xb[8], rb[8];
      ld8(x, xoff + (size_t)sQe0[r] * DIM + cg * 8, xa, bf);
      f32load8(re + (size_t)sQr0[r] * DIM + cg * 8, ra);
      ld8(x, xoff + (size_t)sQe1[r] * DIM + cg * 8, xb, bf);
      f32load8(re + (size_t)sQr1[r] * DIM + cg * 8, rb);
#pragma unroll
      for (int j = 0; j < 8; ++j) o[j] = xa[j] * ra[j] + xb[j] * rb[j];
    }
    *(uint4*)&As[r][cg * 8] = pack8(o);
  }
  __syncthreads();

  const int lane = tid & 63;
  const int w    = tid >> 6;
  const int wm   = w & 1;           // M-half: rows [wm*32, wm*32+32)
  const int wn   = w >> 1;          // N-half: nt' = wn*7 + nt (wn=1 does 6 tiles)
  const int col  = lane & 15;
  const int quad = lane >> 4;
  const int rbase = wm * 32;
  const int nb4  = quad * 4;

  f4v acc[2][7];
#pragma unroll
  for (int mt = 0; mt < 2; ++mt)
#pragma unroll
    for (int nt = 0; nt < 7; ++nt) acc[mt][nt] = (f4v){0.f, 0.f, 0.f, 0.f};

  // GEMM 1 (transposed): acc[mt][nt] = qual^T tile
  {
    const unsigned short* btl = BtQ + (size_t)(wn * 7 * 16 + col) * KP + quad * 8;
#pragma unroll
    for (int kc = 0; kc < 7; ++kc) {
      const int k0 = kc * 32;
      s8v a0 = __builtin_bit_cast(s8v, *(const uint4*)&As[rbase +      col][k0 + quad * 8]);
      s8v a1 = __builtin_bit_cast(s8v, *(const uint4*)&As[rbase + 16 + col][k0 + quad * 8]);
#pragma unroll
      for (int nt = 0; nt < 7; ++nt) {
        if (wn == 0 || nt < 6) {   // nt' < 13
          s8v b = __builtin_bit_cast(s8v, *(const uint4*)(btl + (size_t)nt * 16 * KP + k0));
          acc[0][nt] = __builtin_amdgcn_mfma_f32_16x16x32_bf16(b, a0, acc[0][nt], 0, 0, 0);
          acc[1][nt] = __builtin_amdgcn_mfma_f32_16x16x32_bf16(b, a1, acc[1][nt], 0, 0, 0);
        }
      }
    }
  }
  __syncthreads();   // all GEMM1 reads of t1 complete before any ep1 overwrite

  // epilogue 1: m = x[src] * 0.5*(re[ety] + qual) -> As (8B vector ops)
#pragma unroll
  for (int mt = 0; mt < 2; ++mt) {
    const int erow = rbase + mt * 16 + col;
    const float* rerow = re + (size_t)sEty[erow] * DIM;
    const size_t xrow = xoff + (size_t)sSrc[erow] * DIM;
#pragma unroll
    for (int nt = 0; nt < 7; ++nt) {
      const int n0 = (wn * 7 + nt) * 16 + nb4;
      if (n0 < DIM) {                               // pads (>=200) stay zero from staging
        float xs[4];
        if (bf) {
          us4 u = *(const us4*)((const unsigned short*)x.p + xrow + n0);
          xs[0]=b2f(u[0]); xs[1]=b2f(u[1]); xs[2]=b2f(u[2]); xs[3]=b2f(u[3]);
        } else {
          float4 q = *(const float4*)((const float*)x.p + xrow + n0);
          xs[0]=q.x; xs[1]=q.y; xs[2]=q.z; xs[3]=q.w;
        }
        float4 r4 = *(const float4*)(rerow + n0);
        us4 mu;
        mu[0] = f2b(xs[0] * (0.5f * (r4.x + acc[mt][nt][0])));
        mu[1] = f2b(xs[1] * (0.5f * (r4.y + acc[mt][nt][1])));
        mu[2] = f2b(xs[2] * (0.5f * (r4.z + acc[mt][nt][2])));
        mu[3] = f2b(xs[3] * (0.5f * (r4.w + acc[mt][nt][3])));
        *(us4*)&As[erow][n0] = mu;
      }
    }
  }
  __syncthreads();   // ep1 writes visible to both N-half waves before GEMM2

#pragma unroll
  for (int mt = 0; mt < 2; ++mt)
#pragma unroll
    for (int nt = 0; nt < 7; ++nt) acc[mt][nt] = (f4v){0.f, 0.f, 0.f, 0.f};

  // GEMM 2 (transposed): msg^T = (w_in|w_out) @ m^T
  {
    const unsigned short* btl = BtW + (size_t)(wn * 7 * 16 + col) * KP + quad * 8;
#pragma unroll
    for (int kc = 0; kc < 7; ++kc) {
      const int k0 = kc * 32;
      s8v a0 = __builtin_bit_cast(s8v, *(const uint4*)&As[rbase +      col][k0 + quad * 8]);
      s8v a1 = __builtin_bit_cast(s8v, *(const uint4*)&As[rbase + 16 + col][k0 + quad * 8]);
#pragma unroll
      for (int nt = 0; nt < 7; ++nt) {
        if (wn == 0 || nt < 6) {
          s8v b = __builtin_bit_cast(s8v, *(const uint4*)(btl + (size_t)nt * 16 * KP + k0));
          acc[0][nt] = __builtin_amdgcn_mfma_f32_16x16x32_bf16(b, a0, acc[0][nt], 0, 0, 0);
          acc[1][nt] = __builtin_amdgcn_mfma_f32_16x16x32_bf16(b, a1, acc[1][nt], 0, 0, 0);
        }
      }
    }
  }

  // epilogue 2: msg[sorted_pos] = bf16(acc * norm), 8B vector stores
#pragma unroll
  for (int mt = 0; mt < 2; ++mt) {
    const int erow = rbase + mt * 16 + col;
    const float nv = sN[erow];
    unsigned short* mp = msg + (mrow0 + erow) * DIM;
#pragma unroll
    for (int nt = 0; nt < 7; ++nt) {
      const int n0 = (wn * 7 + nt) * 16 + nb4;
      if (n0 < DIM) {
        us4 mu;
        mu[0] = f2b(acc[mt][nt][0] * nv);
        mu[1] = f2b(acc[mt][nt][1] * nv);
        mu[2] = f2b(acc[mt][nt][2] * nv);
        mu[3] = f2b(acc[mt][nt][3] * nv);
        *(us4*)&mp[n0] = mu;
      }
    }
  }
}

// ---------------- phase B: segmented sum over BOTH sides + fused BN statistics ----
// agg[d] += sum msgIn + sum msgOut (wave-uniform segment loops: all 50 lanes walk the same
// entity d). Fused bn_reduce: per-lane s,s2 over its 16 rows, LDS-reduce across 4 waves,
// 400 atomicAdds/block (grid 625). Deletes the separate 32MB bn_reduce pass.
__global__ __launch_bounds__(256) void segsum_kernel(const unsigned short* __restrict__ msg,
                                                     const int* __restrict__ offsI,
                                                     const int* __restrict__ offsO,
                                                     float4* __restrict__ agg4,
                                                     float* __restrict__ sums) {
  __shared__ float rs[4][50][4];
  __shared__ float rq[4][50][4];
  const int lane = threadIdx.x & 63;
  const int w    = threadIdx.x >> 6;
  if (lane < 50) {
    float s[4] = {0.f, 0.f, 0.f, 0.f};
    float q[4] = {0.f, 0.f, 0.f, 0.f};
    const int rbase = blockIdx.x * 64 + w * 16;
    for (int rr = 0; rr < 16; ++rr) {
      const int d = rbase + rr;
      const size_t ap = (size_t)d * 50 + lane;
      float4 v = agg4[ap];
      int b = offsI[d], e = offsI[d + 1];
      for (int k = b; k < e; ++k) {
        us4 u = *(const us4*)(msg + (size_t)k * DIM + lane * 4);
        v.x += b2f(u[0]); v.y += b2f(u[1]); v.z += b2f(u[2]); v.w += b2f(u[3]);
      }
      b = offsO[d]; e = offsO[d + 1];
      for (int k = b; k < e; ++k) {
        us4 u = *(const us4*)(msg + (size_t)(EE + k) * DIM + lane * 4);
        v.x += b2f(u[0]); v.y += b2f(u[1]); v.z += b2f(u[2]); v.w += b2f(u[3]);
      }
      agg4[ap] = v;
      float t0 = v.x * (1.f / 3.f), t1 = v.y * (1.f / 3.f);
      float t2 = v.z * (1.f / 3.f), t3 = v.w * (1.f / 3.f);
      s[0] += t0; s[1] += t1; s[2] += t2; s[3] += t3;
      q[0] += t0 * t0; q[1] += t1 * t1; q[2] += t2 * t2; q[3] += t3 * t3;
    }
#pragma unroll
    for (int c = 0; c < 4; ++c) { rs[w][lane][c] = s[c]; rq[w][lane][c] = q[c]; }
  }
  __syncthreads();
  const int c = threadIdx.x;
  if (c < DIM) {
    const int ln = c >> 2, ci = c & 3;
    float S = rs[0][ln][ci] + rs[1][ln][ci] + rs[2][ln][ci] + rs[3][ln][ci];
    float Q = rq[0][ln][ci] + rq[1][ln][ci] + rq[2][ln][ci] + rq[3][ln][ci];
    atomicAdd(&sums[c], S);
    atomicAdd(&sums[DIM + c], Q);
  }
}

// ---------------- BatchNorm apply + gather ----------------
__global__ __launch_bounds__(256) void bn_apply_kernel(const float* __restrict__ agg,
                                                       const float* __restrict__ sums,
                                                       MP gamma, MP beta,
                                                       void* __restrict__ xout, size_t ooff,
                                                       const int* __restrict__ flagp) {
  __shared__ float sc[DIM], sh[DIM];
  const int bf = *flagp;
  int tid = threadIdx.x;
  if (tid < DIM) {
    float mean = sums[tid] * (1.f / NENT);
    float var  = sums[DIM + tid] * (1.f / NENT) - mean * mean;
    float s = ld(gamma, tid, bf) * rsqrtf(var + EPSBN);
    sc[tid] = s;
    sh[tid] = ld(beta, tid, bf) - mean * s;
  }
  __syncthreads();
  int stride = gridDim.x * blockDim.x;
  for (int i = blockIdx.x * blockDim.x + tid; i < NENT * DIM; i += stride) {
    int c = i % DIM;
    float v = agg[i] * (1.f / 3.f);
    float z = fmaf(v, sc[c], sh[c]);
    float e = __expf(2.f * z);                 // fast tanh: exact at +-inf, ~1e-7 rel err
    float th = 1.f - 2.f / (e + 1.f);
    st(xout, ooff + i, th, bf);
  }
}

__global__ void gather_kernel(void* __restrict__ out, const float* __restrict__ rfin,
                              const int* __restrict__ sub, const int* __restrict__ rel,
                              const int* __restrict__ flagp) {
  const int bf = *flagp;
  int i = blockIdx.x * 256 + threadIdx.x;
  MP xm; xm.p = out;
  if (i < BQ * DIM) {
    int b = i / DIM, c = i - b * DIM;
    st(out, i, ld(xm, XOFF + (size_t)sub[b] * DIM + c, bf), bf);
  } else if (i < 2 * BQ * DIM) {
    int j = i - BQ * DIM;
    int b = j / DIM, c = j - b * DIM;
    st(out, i, rfin[(size_t)rel[b] * DIM + c], bf);
  }
}

// ---------------- launch ----------------
extern "C" void kernel_launch(void* const* d_in, const int* in_sizes, int n_in,
                              void* d_out, int out_size, void* d_ws, size_t ws_size,
                              hipStream_t stream) {
  (void)in_sizes; (void)n_in; (void)out_size; (void)ws_size;
  const int* ei  = (const int*)d_in[0];
  const int* ety = (const int*)d_in[1];
  const int* qe  = (const int*)d_in[2];
  const int* qr  = (const int*)d_in[3];
  const int* sub = (const int*)d_in[4];
  const int* rel = (const int*)d_in[5];
  MP x0 = { d_in[6] };
  MP ir = { d_in[7] };
  MP w_rel[2]  = { { d_in[11] }, { d_in[20] } };
  MP gamma[2]  = { { d_in[15] }, { d_in[24] } };
  MP beta[2]   = { { d_in[16] }, { d_in[25] } };

  float* ws = (float*)d_ws;
  float* deg_in   = ws;                         // 40000
  float* deg_out  = ws + 40000;                 // 40000
  float* sums1    = ws + 80000;                 // 400
  float* sums2    = ws + 80400;                 // 400
  int*   flag     = (int*)(ws + 80800);         // 16
  float* normA    = ws + 80816;                 // 160000
  float* rel1     = ws + 240816;                // [200,200] f32
  float* rel2     = ws + 280816;
  float* rfin     = ws + 320816;
  unsigned short* bt = (unsigned short*)(ws + 440816);  // 8 x [208][224] bf16 -> ends 627184
  int*   cnt      = (int*)(ws + 627184);        // [2][40000]
  int*   offs     = (int*)(ws + 707184);        // [2][40001]
  int*   tmpo     = (int*)(ws + 787200);        // [2][40000]
  int*   perm     = (int*)(ws + 867200);        // [160000]
  unsigned short* msg = (unsigned short*)(ws + 1027200); // [160000][200] bf16, ends 17027200 < 18547184
  float* agg      = ws + 18547184;              // [40000][200] f32 (offset proven safe in r3)

  hipMemsetAsync(ws, 0, 80800 * sizeof(float), stream);       // deg + sums
  hipMemsetAsync(cnt, 0, 2 * NENT * sizeof(int), stream);     // dst counts

  detect_kernel<<<1, 64, 0, stream>>>((const unsigned short*)d_in[6], flag);
  edge_hist_kernel<<<(TOTE + 255) / 256, 256, 0, stream>>>(ei, deg_in, deg_out, cnt);
  norm_kernel<<<(TOTE + 255) / 256, 256, 0, stream>>>(ei, deg_in, deg_out, normA);
  scan_kernel<<<2, 256, 0, stream>>>(cnt, offs, tmpo);
  scatter_kernel<<<(TOTE + 255) / 256, 256, 0, stream>>>(ei, tmpo, perm);
  copy_f32_kernel<<<(DIM * DIM + 255) / 256, 256, 0, stream>>>(ir, rel1, DIM * DIM, flag);
  mat200_kernel<<<DIM, 256, 0, stream>>>(ir, 1, w_rel[0], rel2, flag);
  MP rel2m = { rel2 };
  mat200_kernel<<<DIM, 256, 0, stream>>>(rel2m, 0, w_rel[1], rfin, flag);

  // Bt: [0]=wq1 [1]=win1 [2]=wout1 [3]=wp1 [4]=wq2 [5]=win2 [6]=wout2 [7]=wp2 (one launch)
  BtArgs ba;
  ba.w[0] = d_in[12]; ba.lr[0] = nullptr;   ba.has[0] = 0;   // wq1
  ba.w[1] = d_in[9];  ba.lr[1] = nullptr;   ba.has[1] = 0;   // win1
  ba.w[2] = d_in[10]; ba.lr[2] = nullptr;   ba.has[2] = 0;   // wout1
  ba.w[3] = d_in[8];  ba.lr[3] = d_in[13];  ba.has[3] = 1;   // wp1 = w_loop1 * loop_rel1
  ba.w[4] = d_in[21]; ba.lr[4] = nullptr;   ba.has[4] = 0;   // wq2
  ba.w[5] = d_in[18]; ba.lr[5] = nullptr;   ba.has[5] = 0;   // win2
  ba.w[6] = d_in[19]; ba.lr[6] = nullptr;   ba.has[6] = 0;   // wout2
  ba.w[7] = d_in[17]; ba.lr[7] = d_in[22];  ba.has[7] = 1;   // wp2 = w_loop2 * loop_rel2
  btprep_all_kernel<<<dim3(NP, 8), 256, 0, stream>>>(ba, bt, flag);

  MP x1 = { d_out };
  const int* offsI = offs;
  const int* offsO = offs + (NENT + 1);

  // ---- layer 1 ----
  edge_msg<<<2 * MT_SIDE, 256, 0, stream>>>(x0, 0, rel1, ei, ety, qe, qr, normA, perm,
                                            bt + 0ull * NP * KP, bt + 1ull * NP * KP,
                                            bt + 2ull * NP * KP, msg, flag);
  loop_mfma<<<MT_LOOP, 256, 0, stream>>>(x0, 0, bt + 3ull * NP * KP, agg, flag);
  segsum_kernel<<<NENT / 64, 256, 0, stream>>>(msg, offsI, offsO, (float4*)agg, sums1);
  bn_apply_kernel<<<2048, 256, 0, stream>>>(agg, sums1, gamma[0], beta[0], d_out, XOFF, flag);

  // ---- layer 2 (x1 lives in d_out x-region) ----
  edge_msg<<<2 * MT_SIDE, 256, 0, stream>>>(x1, XOFF, rel2, ei, ety, qe, qr, normA, perm,
                                            bt + 4ull * NP * KP, bt + 5ull * NP * KP,
                                            bt + 6ull * NP * KP, msg, flag);
  loop_mfma<<<MT_LOOP, 256, 0, stream>>>(x1, XOFF, bt + 7ull * NP * KP, agg, flag);
  segsum_kernel<<<NENT / 64, 256, 0, stream>>>(msg, offsI, offsO, (float4*)agg, sums2);
  bn_apply_kernel<<<2048, 256, 0, stream>>>(agg, sums2, gamma[1], beta[1], d_out, XOFF, flag);

  gather_kernel<<<(2 * BQ * DIM + 255) / 256, 256, 0, stream>>>(d_out, rfin, sub, rel, flag);
}